// Round 4
// baseline (270.287 us; speedup 1.0000x reference)
//
#include <hip/hip_runtime.h>

// DropNorm: B=4096 rows, F=8192 features, fp32.
//   n = F/2; mu = sum(x*m)/n; sigma2 = sum(((x-mu)*m)^2)/(n-1)
//   out = gamma*m*(x-mu)*rsqrt(sigma2^2 + 1e-4) + beta   [sigma2 SQUARED: quirk]
//
// R7: persistent 4-row blocks + cross-row prefetch + NON-DRAINING barrier.
//   R6 post-mortem: re-reading x doubled FETCH (65.8->120.5 MB) -> re-read
//   went to HBM, not L2/L3. Net -11%. Constraint restored: read x ONCE.
//   Shared flaw of all ~80us versions: at the reduction barrier the wave has
//   zero HBM reads in flight — __syncthreads drains vmcnt(0) (compiler
//   semantics), and the compiler sinks "early" loads anyway (R4: VGPR=56).
//   Fix (8-phase/HK pattern, plain HIP):
//     - block owns 4 consecutive rows; all 1024 blocks co-resident (16 w/CU).
//     - per row: issue next-row x loads + mg loads, sched_barrier(0) pins
//       them BEFORE the accumulate (no sinking), accumulate uses counted
//       vmcnt waits (no drain), reduce via shuffle + LDS partials with
//       ping-pong parity + asm lgkmcnt(0) + RAW s_barrier (prefetch stays
//       in flight across the barrier), beta loads post-barrier, FMA + NT store.
//   x: 1 read. out: 1 NT write. params: L2-hot per-row re-reads.

constexpr int Bn = 4096;
constexpr int Fn = 8192;
constexpr int NT = 256;           // threads per block
constexpr int PT = Fn / (NT * 4); // 8 f4 chunks per thread per row
constexpr int RPB = 4;            // rows per block

typedef float f4 __attribute__((ext_vector_type(4)));

#define EPSV 1e-4f

__device__ inline int nzbytes(unsigned v) {
    return ((v & 0x000000ffu) != 0) + ((v & 0x0000ff00u) != 0) +
           ((v & 0x00ff0000u) != 0) + ((v & 0xff000000u) != 0);
}

// Prep: detect mask storage layout (uint8 bool vs int32), then materialize
//   mg[j]    = mask ? gamma[j] : 0.0                    (Fn floats)
//   bitpk[t] = packed mask bits for thread t:
//              bit (4k+j) = mask[4*(t + k*NT) + j]      (NT uint32)
// Detection: count nonzero among the first Fn BYTES. uint8 layout -> exactly
// Fn/2 = 4096; int32 layout -> those bytes span only 2048 ints -> count <= 2048.
__global__ __launch_bounds__(NT) void prep_kernel(const void* __restrict__ mask_raw,
                                                  const float* __restrict__ gamma,
                                                  unsigned* __restrict__ bitpk,
                                                  float* __restrict__ mg) {
    const unsigned char* mb = (const unsigned char*)mask_raw;
    const int* mi = (const int*)mask_raw;
    const uint4* mv = (const uint4*)mask_raw;
    const int tid = threadIdx.x;

    int cnt = 0;
#pragma unroll
    for (int k = 0; k < Fn / 16 / NT; ++k) {   // 2 iterations
        const uint4 w = mv[tid + k * NT];
        cnt += nzbytes(w.x) + nzbytes(w.y) + nzbytes(w.z) + nzbytes(w.w);
    }
    for (int off = 32; off > 0; off >>= 1) cnt += __shfl_down(cnt, off, 64);

    __shared__ int wc[NT / 64];
    __shared__ int flag;
    if ((tid & 63) == 0) wc[tid >> 6] = cnt;
    __syncthreads();
    if (tid == 0) {
        int total = wc[0] + wc[1] + wc[2] + wc[3];
        flag = (total == Fn / 2) ? 1 : 0;   // 1 = uint8 layout, 0 = int32 layout
    }
    __syncthreads();
    const bool u8 = (flag != 0);

    const int per_block = Fn / gridDim.x;
    const int base = blockIdx.x * per_block;
    for (int j = base + tid; j < base + per_block; j += NT) {
        const bool on = u8 ? (mb[j] != 0) : (mi[j] != 0);
        mg[j] = on ? gamma[j] : 0.0f;
    }

    if (blockIdx.x == 0) {
        unsigned w = 0;
#pragma unroll
        for (int k = 0; k < PT; ++k) {
#pragma unroll
            for (int j = 0; j < 4; ++j) {
                const int f = 4 * (tid + k * NT) + j;
                const bool on = u8 ? (mb[f] != 0) : (mi[f] != 0);
                w |= (on ? 1u : 0u) << (4 * k + j);
            }
        }
        bitpk[tid] = w;
    }
}

// One pipelined row stage. PF: prefetch row (rowi+1) into NXT. PAR: LDS
// partial-buffer parity (ping-pong => one raw barrier per row is enough:
// re-write of parity p is separated from its readers by the barrier at p^1).
#define STAGE(PF, PAR, ROWI, CUR, NXT)                                         \
    {                                                                          \
        if (PF) {                                                              \
            const f4* __restrict__ xn =                                        \
                (const f4*)(x + (size_t)(row0 + (ROWI) + 1) * Fn);             \
            _Pragma("unroll")                                                  \
            for (int k = 0; k < PT; ++k) NXT[k] = xn[tid + k * NT];            \
        }                                                                      \
        f4 gv[PT];                                                             \
        _Pragma("unroll")                                                      \
        for (int k = 0; k < PT; ++k) gv[k] = g4[tid + k * NT];                 \
        __builtin_amdgcn_sched_barrier(0); /* pin loads ABOVE the compute */   \
        float s = 0.f, ss = 0.f;                                               \
        _Pragma("unroll")                                                      \
        for (int k = 0; k < PT; ++k) {                                         \
            const f4 v = CUR[k];                                               \
            const float a0 = ((mbits >> (4 * k + 0)) & 1u) ? v.x : 0.f;        \
            const float a1 = ((mbits >> (4 * k + 1)) & 1u) ? v.y : 0.f;        \
            const float a2 = ((mbits >> (4 * k + 2)) & 1u) ? v.z : 0.f;        \
            const float a3 = ((mbits >> (4 * k + 3)) & 1u) ? v.w : 0.f;        \
            s  += (a0 + a1) + (a2 + a3);                                       \
            ss += (a0 * a0 + a1 * a1) + (a2 * a2 + a3 * a3);                   \
        }                                                                      \
        for (int off = 32; off > 0; off >>= 1) {                               \
            s  += __shfl_down(s, off, 64);                                     \
            ss += __shfl_down(ss, off, 64);                                    \
        }                                                                      \
        if ((tid & 63) == 0) { rs[PAR][wid] = s; rss[PAR][wid] = ss; }         \
        asm volatile("s_waitcnt lgkmcnt(0)" ::: "memory");                     \
        __builtin_amdgcn_s_barrier(); /* RAW: no vmcnt drain */                \
        asm volatile("" ::: "memory");                                         \
        f4 bv[PT];                                                             \
        _Pragma("unroll")                                                      \
        for (int k = 0; k < PT; ++k) bv[k] = b4[tid + k * NT];                 \
        const float S  = (rs[PAR][0] + rs[PAR][1]) + (rs[PAR][2] + rs[PAR][3]);\
        const float SS = (rss[PAR][0] + rss[PAR][1]) +                         \
                         (rss[PAR][2] + rss[PAR][3]);                          \
        const float mu = S / nf;                                               \
        const float sigma2 = (SS - nf * mu * mu) / (nf - 1.0f);                \
        const float inv = rsqrtf(sigma2 * sigma2 + EPSV); /* quirk: ^2 */      \
        f4* __restrict__ o4 = (f4*)(out + (size_t)(row0 + (ROWI)) * Fn);       \
        _Pragma("unroll")                                                      \
        for (int k = 0; k < PT; ++k) {                                         \
            const f4 v = CUR[k];                                               \
            f4 o;                                                              \
            o.x = gv[k].x * (v.x - mu) * inv + bv[k].x;                        \
            o.y = gv[k].y * (v.y - mu) * inv + bv[k].y;                        \
            o.z = gv[k].z * (v.z - mu) * inv + bv[k].z;                        \
            o.w = gv[k].w * (v.w - mu) * inv + bv[k].w;                        \
            __builtin_nontemporal_store(o, o4 + tid + k * NT);                 \
        }                                                                      \
    }

__global__ __launch_bounds__(NT, 4) void dropnorm_kernel(const float* __restrict__ x,
                                                         const unsigned* __restrict__ bitpk,
                                                         const float* __restrict__ mg,
                                                         const float* __restrict__ beta,
                                                         float* __restrict__ out) {
    __shared__ float rs[2][NT / 64], rss[2][NT / 64];

    const int tid = threadIdx.x;
    const int wid = tid >> 6;
    const int row0 = blockIdx.x * RPB;
    const float nf = (float)(Fn / 2);

    const f4* __restrict__ g4 = (const f4*)mg;
    const f4* __restrict__ b4 = (const f4*)beta;

    const unsigned mbits = bitpk[tid];

    f4 xa[PT], xb[PT];

    // prologue: first row into xa
    {
        const f4* __restrict__ xr = (const f4*)(x + (size_t)row0 * Fn);
#pragma unroll
        for (int k = 0; k < PT; ++k) xa[k] = xr[tid + k * NT];
    }

    STAGE(true,  0, 0, xa, xb)
    STAGE(true,  1, 1, xb, xa)
    STAGE(true,  0, 2, xa, xb)
    STAGE(false, 1, 3, xb, xa)
}

extern "C" void kernel_launch(void* const* d_in, const int* in_sizes, int n_in,
                              void* d_out, int out_size, void* d_ws, size_t ws_size,
                              hipStream_t stream) {
    const float* x     = (const float*)d_in[0];
    const float* gamma = (const float*)d_in[1];
    const float* beta  = (const float*)d_in[2];
    const void*  mask  = d_in[3];
    float* out = (float*)d_out;

    float* mg = (float*)d_ws;                      // Fn floats
    unsigned* bitpk = (unsigned*)(mg + Fn);        // NT uint32

    prep_kernel<<<16, NT, 0, stream>>>(mask, gamma, bitpk, mg);
    dropnorm_kernel<<<Bn / RPB, NT, 0, stream>>>(x, bitpk, mg, beta, out);
}

// Round 5
// 249.964 us; speedup vs baseline: 1.0813x; 1.0813x over previous
//
#include <hip/hip_runtime.h>

// DropNorm: B=4096 rows, F=8192 features, fp32.
//   n = F/2; mu = sum(x*m)/n; sigma2 = sum(((x-mu)*m)^2)/(n-1)
//   out = gamma*m*(x-mu)*rsqrt(sigma2^2 + 1e-4) + beta   [sigma2 SQUARED: quirk]
//
// R8: LDS-homed rows via global_load_lds DMA + counted vmcnt (m201/T3+T4).
//   R7 post-mortem: VGPR=64 + WRITE 131->204.5MB + FETCH 65->123MB = the
//   compiler SPILLED the register row buffers (xa/xb/gv/bv ~160 regs > 128
//   cap). Three rounds prove: VGPRs are not a safe home for a 32KB row
//   across a reduction (R4 sank, R7 spilled).
//   Fix: row lives in LDS, filled by zero-VGPR async DMA:
//     - 512 blocks x 8 rows; 2 x 32KB LDS row buffers (ping-pong).
//     - per row: s_waitcnt vmcnt(8/16) COUNTED (never 0) -> next row's DMA
//       stays in flight across the reduction barrier; accumulate + apply
//       both ds_read from LDS; ONE raw s_barrier per row (partials only —
//       each wave's DMA quarter is read only by that wave, so buffer reuse
//       is wave-local and needs no barrier).
//     - sched_barrier(0) between DMA batches pins vmcnt FIFO order.
//     - gv/bv loop-invariant, hoisted once (64 VGPR); total ~100, no spill.
//   Tripwires: WRITE_SIZE must return to ~131MB, FETCH to ~66MB.

constexpr int Bn = 4096;
constexpr int Fn = 8192;
constexpr int NT = 256;           // threads per block
constexpr int PT = Fn / (NT * 4); // 8 f4 chunks per thread per row
constexpr int RPB = 8;            // rows per block -> grid 512, 2 blocks/CU (LDS-capped)

typedef float f4 __attribute__((ext_vector_type(4)));

#define EPSV 1e-4f

__device__ __forceinline__ void cp16(const void* g, void* l) {
    // async global->LDS, 16B per lane; LDS dest = wave-uniform base + lane*16
    __builtin_amdgcn_global_load_lds(
        (const __attribute__((address_space(1))) void*)g,
        (__attribute__((address_space(3))) void*)l, 16, 0, 0);
}

__device__ inline int nzbytes(unsigned v) {
    return ((v & 0x000000ffu) != 0) + ((v & 0x0000ff00u) != 0) +
           ((v & 0x00ff0000u) != 0) + ((v & 0xff000000u) != 0);
}

// Prep: detect mask storage layout (uint8 bool vs int32), then materialize
//   mg[j]    = mask ? gamma[j] : 0.0                    (Fn floats)
//   bitpk[t] = packed mask bits for thread t:
//              bit (4k+j) = mask[4*(t + k*NT) + j]      (NT uint32)
// Detection: count nonzero among the first Fn BYTES. uint8 layout -> exactly
// Fn/2 = 4096; int32 layout -> those bytes span only 2048 ints -> count <= 2048.
__global__ __launch_bounds__(NT) void prep_kernel(const void* __restrict__ mask_raw,
                                                  const float* __restrict__ gamma,
                                                  unsigned* __restrict__ bitpk,
                                                  float* __restrict__ mg) {
    const unsigned char* mb = (const unsigned char*)mask_raw;
    const int* mi = (const int*)mask_raw;
    const uint4* mv = (const uint4*)mask_raw;
    const int tid = threadIdx.x;

    int cnt = 0;
#pragma unroll
    for (int k = 0; k < Fn / 16 / NT; ++k) {   // 2 iterations
        const uint4 w = mv[tid + k * NT];
        cnt += nzbytes(w.x) + nzbytes(w.y) + nzbytes(w.z) + nzbytes(w.w);
    }
    for (int off = 32; off > 0; off >>= 1) cnt += __shfl_down(cnt, off, 64);

    __shared__ int wc[NT / 64];
    __shared__ int flag;
    if ((tid & 63) == 0) wc[tid >> 6] = cnt;
    __syncthreads();
    if (tid == 0) {
        int total = wc[0] + wc[1] + wc[2] + wc[3];
        flag = (total == Fn / 2) ? 1 : 0;   // 1 = uint8 layout, 0 = int32 layout
    }
    __syncthreads();
    const bool u8 = (flag != 0);

    const int per_block = Fn / gridDim.x;
    const int base = blockIdx.x * per_block;
    for (int j = base + tid; j < base + per_block; j += NT) {
        const bool on = u8 ? (mb[j] != 0) : (mi[j] != 0);
        mg[j] = on ? gamma[j] : 0.0f;
    }

    if (blockIdx.x == 0) {
        unsigned w = 0;
#pragma unroll
        for (int k = 0; k < PT; ++k) {
#pragma unroll
            for (int j = 0; j < 4; ++j) {
                const int f = 4 * (tid + k * NT) + j;
                const bool on = u8 ? (mb[f] != 0) : (mi[f] != 0);
                w |= (on ? 1u : 0u) << (4 * k + j);
            }
        }
        bitpk[tid] = w;
    }
}

// Issue the 8 per-thread DMA ops for row (row0+RI) into lbuf[P], then pin
// batch order in the vmcnt FIFO so counted waits are exact.
#define DMA_ROW(RI, P)                                                         \
    {                                                                          \
        const f4* __restrict__ xs = (const f4*)(x + (size_t)(row0 + (RI)) * Fn);\
        _Pragma("unroll")                                                      \
        for (int k = 0; k < PT; ++k)                                           \
            cp16(xs + tid + k * NT, &lbuf[P][(wid << 6) + k * NT]);            \
        __builtin_amdgcn_sched_barrier(0);                                     \
    }

// One row stage. VM: counted vmcnt guaranteeing row R's DMA retired while
// younger ops (next row's DMA and/or previous row's stores) stay in flight.
#define ROW(R, P, VM)                                                          \
    {                                                                          \
        asm volatile("s_waitcnt vmcnt(%0)" ::"i"(VM) : "memory");              \
        float s = 0.f, ss = 0.f;                                               \
        _Pragma("unroll")                                                      \
        for (int k = 0; k < PT; ++k) {                                         \
            const f4 v = lbuf[P][tid + k * NT];                                \
            const float a0 = ((mbits >> (4 * k + 0)) & 1u) ? v.x : 0.f;        \
            const float a1 = ((mbits >> (4 * k + 1)) & 1u) ? v.y : 0.f;        \
            const float a2 = ((mbits >> (4 * k + 2)) & 1u) ? v.z : 0.f;        \
            const float a3 = ((mbits >> (4 * k + 3)) & 1u) ? v.w : 0.f;        \
            s  += (a0 + a1) + (a2 + a3);                                       \
            ss += (a0 * a0 + a1 * a1) + (a2 * a2 + a3 * a3);                   \
        }                                                                      \
        for (int off = 32; off > 0; off >>= 1) {                               \
            s  += __shfl_down(s, off, 64);                                     \
            ss += __shfl_down(ss, off, 64);                                    \
        }                                                                      \
        if ((tid & 63) == 0) { rs[P][wid] = s; rss[P][wid] = ss; }             \
        asm volatile("s_waitcnt lgkmcnt(0)" ::: "memory");                     \
        __builtin_amdgcn_s_barrier(); /* raw: DMA stays in flight */           \
        const float S  = (rs[P][0] + rs[P][1]) + (rs[P][2] + rs[P][3]);        \
        const float SS = (rss[P][0] + rss[P][1]) + (rss[P][2] + rss[P][3]);    \
        const float mu = S / nf;                                               \
        const float sigma2 = (SS - nf * mu * mu) / (nf - 1.0f);                \
        const float inv = rsqrtf(sigma2 * sigma2 + EPSV); /* quirk: ^2 */      \
        f4* __restrict__ o4 = (f4*)(out + (size_t)(row0 + (R)) * Fn);          \
        _Pragma("unroll")                                                      \
        for (int k = 0; k < PT; ++k) {                                         \
            const f4 v = lbuf[P][tid + k * NT];                                \
            f4 o;                                                              \
            o.x = gv[k].x * (v.x - mu) * inv + bv[k].x;                        \
            o.y = gv[k].y * (v.y - mu) * inv + bv[k].y;                        \
            o.z = gv[k].z * (v.z - mu) * inv + bv[k].z;                        \
            o.w = gv[k].w * (v.w - mu) * inv + bv[k].w;                        \
            __builtin_nontemporal_store(o, o4 + tid + k * NT);                 \
        }                                                                      \
        asm volatile("s_waitcnt lgkmcnt(0)" ::: "memory"); /* lbuf reads done */\
        if ((R) + 2 < RPB) DMA_ROW((R) + 2, P)                                 \
    }

__global__ __launch_bounds__(NT) void dropnorm_kernel(const float* __restrict__ x,
                                                      const unsigned* __restrict__ bitpk,
                                                      const float* __restrict__ mg,
                                                      const float* __restrict__ beta,
                                                      float* __restrict__ out) {
    __shared__ f4 lbuf[2][Fn / 4];                // 2 x 32 KB row images
    __shared__ float rs[2][NT / 64], rss[2][NT / 64];

    const int tid = threadIdx.x;
    const int wid = tid >> 6;
    const int row0 = blockIdx.x * RPB;
    const float nf = (float)(Fn / 2);

    const f4* __restrict__ g4 = (const f4*)mg;
    const f4* __restrict__ b4 = (const f4*)beta;
    const unsigned mbits = bitpk[tid];

    // loop-invariant params, hoisted once (64 VGPR; L2-hot)
    f4 gv[PT], bv[PT];
#pragma unroll
    for (int k = 0; k < PT; ++k) gv[k] = g4[tid + k * NT];
#pragma unroll
    for (int k = 0; k < PT; ++k) bv[k] = b4[tid + k * NT];

    // DMA prologue: rows 0 and 1
    DMA_ROW(0, 0)
    DMA_ROW(1, 1)

    // vmcnt accounting (per wave, FIFO): at row r's wait, ops younger than
    // row r's 8 DMAs are: next row's 8 DMAs (if issued) + prev row's 8 NT
    // stores (if any). First row: 8. Middle rows: 16. Last row: 8.
    ROW(0, 0, 8)
    ROW(1, 1, 16)
    ROW(2, 0, 16)
    ROW(3, 1, 16)
    ROW(4, 0, 16)
    ROW(5, 1, 16)
    ROW(6, 0, 16)
    ROW(7, 1, 8)
}

extern "C" void kernel_launch(void* const* d_in, const int* in_sizes, int n_in,
                              void* d_out, int out_size, void* d_ws, size_t ws_size,
                              hipStream_t stream) {
    const float* x     = (const float*)d_in[0];
    const float* gamma = (const float*)d_in[1];
    const float* beta  = (const float*)d_in[2];
    const void*  mask  = d_in[3];
    float* out = (float*)d_out;

    float* mg = (float*)d_ws;                      // Fn floats
    unsigned* bitpk = (unsigned*)(mg + Fn);        // NT uint32

    prep_kernel<<<16, NT, 0, stream>>>(mask, gamma, bitpk, mg);
    dropnorm_kernel<<<Bn / RPB, NT, 0, stream>>>(x, bitpk, mg, beta, out);
}